// Round 15
// baseline (471.337 us; speedup 1.0000x reference)
//
#include <hip/hip_runtime.h>

#define NN 50000
#define EE 800000
#define ET (EE + NN)
#define HID 256
#define NH 8
#define HC 32
#define OC 64
#define PC 128   // layer-3 projected width (mu||logstd)

typedef unsigned int u32;
typedef unsigned short u16s;
typedef _Float16 f16;
typedef __attribute__((ext_vector_type(8))) _Float16 f16x8;
typedef __attribute__((ext_vector_type(4))) _Float16 f16x4;
typedef __attribute__((ext_vector_type(4))) float f32x4;

static __device__ __forceinline__ float geluf(float x){
  float t = tanhf(0.7978845608028654f*(x + 0.044715f*x*x*x));
  return 0.5f*x*(1.0f+t);
}
static __device__ __forceinline__ float leakyf(float x){
  return x > 0.0f ? x : 0.2f*x;
}

// ---------------- CSR build ----------------
__global__ void k_count(const int* __restrict__ dst, u32* __restrict__ cnt){
  int e = blockIdx.x*blockDim.x + threadIdx.x;
  if (e < EE) atomicAdd(&cnt[dst[e]], 1u);
}
// wave-aggregated bump allocation: 1 atomic per wave (G12). Adds self-loop (+1).
__global__ void k_alloc(u32* __restrict__ cnt, u32* counter,
                        u32* __restrict__ start, u32* __restrict__ pos,
                        float* __restrict__ dinv){
  int n = blockIdx.x*blockDim.x + threadIdx.x;
  const int lane = threadIdx.x & 63;
  u32 c = (n < NN) ? (cnt[n] + 1u) : 0u;   // +1 self loop
  u32 pre = c;                          // wave-inclusive prefix sum
  #pragma unroll
  for (int off=1; off<64; off<<=1){
    u32 v = __shfl_up(pre, off);
    if (lane >= off) pre += v;
  }
  u32 tot = __shfl(pre, 63);
  u32 base = 0;
  if (lane == 63) base = atomicAdd(counter, tot);
  base = __shfl(base, 63);
  if (n < NN){
    u32 s = base + pre - c;             // exclusive
    start[n] = s; pos[n] = s;
    dinv[n] = rsqrtf((float)c);
    cnt[n] = c;                         // store total (incl self loop)
  }
}
__global__ void k_fill(const int* __restrict__ src, const int* __restrict__ dst,
                       u32* __restrict__ pos, u16s* __restrict__ col,
                       const float* __restrict__ dinv, float* __restrict__ nrmE){
  int e = blockIdx.x*blockDim.x + threadIdx.x;
  if (e < ET){
    int s, d;
    if (e < EE){ s = src[e]; d = dst[e]; } else { s = d = e - EE; }
    u32 idx = atomicAdd(&pos[d], 1u);
    col[idx] = (u16s)s;
    nrmE[idx] = dinv[s] * dinv[d];
  }
}

// ---------------- all weight splits in one kernel ----------------
// W[K=256][NC] f32 row-major -> hi/lo f16 col-major
#define W1N (HID*HID)
__global__ void k_wsplit_all(const float* __restrict__ w1, const float* __restrict__ watt,
    const float* __restrict__ wmu, const float* __restrict__ wls,
    f16* __restrict__ w1h, f16* __restrict__ w1l,
    f16* __restrict__ wah, f16* __restrict__ wal,
    f16* __restrict__ wch, f16* __restrict__ wcl){
  int e = blockIdx.x*blockDim.x + threadIdx.x;
  const float* W; f16 *H, *L; int NC, coff = 0, idx;
  if (e < W1N){ W=w1; H=w1h; L=w1l; NC=HID; idx=e; }
  else if (e < 2*W1N){ W=watt; H=wah; L=wal; NC=HID; idx=e-W1N; }
  else if (e < 2*W1N + OC*HID){ W=wmu; H=wch; L=wcl; NC=OC; idx=e-2*W1N; }
  else if (e < 2*W1N + 2*OC*HID){ W=wls; H=wch; L=wcl; NC=OC; coff=OC; idx=e-2*W1N-OC*HID; }
  else return;
  int c = idx / HID, k = idx % HID;
  float w = W[(size_t)k*NC + c];
  f16 hi = (f16)w;
  f16 lo = (f16)(w - (float)hi);
  H[(size_t)(c+coff)*HID + k] = hi;
  L[(size_t)(c+coff)*HID + k] = lo;
}

// ---------------- GEMM (f32 A converted in-reg, 2-pass f16 W, MR rows, NCB col-split) ----------------
// grid = rowblocks*NCB; cb = bid&(NCB-1) (consecutive blocks share A rows -> L2 reuse)
template<int NC, int NF, int MR, int NCB>
__global__ __launch_bounds__(256) void k_gemm_fx(const float* __restrict__ A,
    const f16* __restrict__ Whi, const f16* __restrict__ Wlo, f16* __restrict__ Cout){
  const int tid = threadIdx.x;
  const int w = tid >> 6, lane = tid & 63;
  const int r = lane & 15, g = lane >> 4;
  const int cb = blockIdx.x & (NCB-1);
  const int row0 = (blockIdx.x / NCB) * (MR*16);
  const int wcol = cb*(NC/NCB) + w*(NF*16);
  f32x4 acc[MR][NF];
  #pragma unroll
  for (int m=0;m<MR;++m)
    #pragma unroll
    for (int j=0;j<NF;++j){ f32x4 z = {0.f,0.f,0.f,0.f}; acc[m][j] = z; }
  #pragma unroll
  for (int kk=0; kk<8; ++kk){
    const int k0 = kk*32 + g*8;
    f16x8 a[MR];
    #pragma unroll
    for (int m=0;m<MR;++m){
      const int row = row0 + m*16 + r;
      f16x8 v = {0,0,0,0,0,0,0,0};
      if (row < NN){
        const float* ap = A + (size_t)row*HID + k0;
        const float4 u0 = *(const float4*)ap;
        const float4 u1 = *(const float4*)(ap+4);
        v[0]=(f16)u0.x; v[1]=(f16)u0.y; v[2]=(f16)u0.z; v[3]=(f16)u0.w;
        v[4]=(f16)u1.x; v[5]=(f16)u1.y; v[6]=(f16)u1.z; v[7]=(f16)u1.w;
      }
      a[m] = v;
    }
    #pragma unroll
    for (int j=0;j<NF;++j){
      const int c = wcol + j*16 + r;
      const size_t off = (size_t)c*HID + k0;
      const f16x8 wh = *(const f16x8*)(Whi + off);
      const f16x8 wl = *(const f16x8*)(Wlo + off);
      #pragma unroll
      for (int m=0;m<MR;++m){
        acc[m][j] = __builtin_amdgcn_mfma_f32_16x16x32_f16(a[m], wh, acc[m][j], 0, 0, 0);
        acc[m][j] = __builtin_amdgcn_mfma_f32_16x16x32_f16(a[m], wl, acc[m][j], 0, 0, 0);
      }
    }
  }
  #pragma unroll
  for (int j=0;j<NF;++j){
    const int c = wcol + j*16 + r;
    #pragma unroll
    for (int m=0;m<MR;++m){
      #pragma unroll
      for (int q=0;q<4;++q){
        const int row = row0 + m*16 + g*4 + q;
        if (row < NN) Cout[(size_t)row*NC + c] = (f16)acc[m][j][q];
      }
    }
  }
}

// ---------------- GEMM (f16 A, 2-pass f16 W split, MR rows, NCB col-split) ----------------
template<int NC, int NF, int MR, int NCB>
__global__ __launch_bounds__(256) void k_gemm_f16A(const f16* __restrict__ A,
    const f16* __restrict__ Whi, const f16* __restrict__ Wlo, f16* __restrict__ Cout){
  const int tid = threadIdx.x;
  const int w = tid >> 6, lane = tid & 63;
  const int r = lane & 15, g = lane >> 4;
  const int cb = blockIdx.x & (NCB-1);
  const int row0 = (blockIdx.x / NCB) * (MR*16);
  const int wcol = cb*(NC/NCB) + w*(NF*16);
  f32x4 acc[MR][NF];
  #pragma unroll
  for (int m=0;m<MR;++m)
    #pragma unroll
    for (int j=0;j<NF;++j){ f32x4 z = {0.f,0.f,0.f,0.f}; acc[m][j] = z; }
  #pragma unroll
  for (int kk=0; kk<8; ++kk){
    const int k0 = kk*32 + g*8;
    f16x8 a[MR];
    #pragma unroll
    for (int m=0;m<MR;++m){
      const int row = row0 + m*16 + r;
      f16x8 z = {0,0,0,0,0,0,0,0};
      a[m] = (row < NN) ? *(const f16x8*)(A + (size_t)row*HID + k0) : z;
    }
    #pragma unroll
    for (int j=0;j<NF;++j){
      const int c = wcol + j*16 + r;
      const size_t off = (size_t)c*HID + k0;
      const f16x8 wh = *(const f16x8*)(Whi + off);
      const f16x8 wl = *(const f16x8*)(Wlo + off);
      #pragma unroll
      for (int m=0;m<MR;++m){
        acc[m][j] = __builtin_amdgcn_mfma_f32_16x16x32_f16(a[m], wh, acc[m][j], 0, 0, 0);
        acc[m][j] = __builtin_amdgcn_mfma_f32_16x16x32_f16(a[m], wl, acc[m][j], 0, 0, 0);
      }
    }
  }
  #pragma unroll
  for (int j=0;j<NF;++j){
    const int c = wcol + j*16 + r;
    #pragma unroll
    for (int m=0;m<MR;++m){
      #pragma unroll
      for (int q=0;q<4;++q){
        const int row = row0 + m*16 + g*4 + q;
        if (row < NN) Cout[(size_t)row*NC + c] = (f16)acc[m][j][q];
      }
    }
  }
}

// ---------------- GAT GEMM (f16 A, col-split NCB=2, NF=2) + fused attention coefficients ----------------
// Each wave owns exactly ONE head: head = cb*4 + w (32 cols). Attention dots reduce
// within the wave via shuffle over r-lanes; no LDS.
__global__ __launch_bounds__(256) void k_gemm_att(const f16* __restrict__ A,
    const f16* __restrict__ Whi, const f16* __restrict__ Wlo,
    const float* __restrict__ atts, const float* __restrict__ attd,
    f16* __restrict__ Cout, float* __restrict__ a_src, float* __restrict__ a_dst){
  const int tid = threadIdx.x;
  const int w = tid >> 6, lane = tid & 63;
  const int r = lane & 15, g = lane >> 4;
  const int cb = blockIdx.x & 1;
  const int row0 = (blockIdx.x >> 1) * 64;
  const int wcol = cb*128 + w*32;
  const int head = cb*4 + w;
  f32x4 acc[4][2];
  #pragma unroll
  for (int m=0;m<4;++m)
    #pragma unroll
    for (int j=0;j<2;++j){ f32x4 z = {0.f,0.f,0.f,0.f}; acc[m][j] = z; }
  #pragma unroll
  for (int kk=0; kk<8; ++kk){
    const int k0 = kk*32 + g*8;
    f16x8 a[4];
    #pragma unroll
    for (int m=0;m<4;++m){
      const int row = row0 + m*16 + r;
      f16x8 z = {0,0,0,0,0,0,0,0};
      a[m] = (row < NN) ? *(const f16x8*)(A + (size_t)row*HID + k0) : z;
    }
    #pragma unroll
    for (int j=0;j<2;++j){
      const int c = wcol + j*16 + r;
      const size_t off = (size_t)c*HID + k0;
      const f16x8 wh = *(const f16x8*)(Whi + off);
      const f16x8 wl = *(const f16x8*)(Wlo + off);
      #pragma unroll
      for (int m=0;m<4;++m){
        acc[m][j] = __builtin_amdgcn_mfma_f32_16x16x32_f16(a[m], wh, acc[m][j], 0, 0, 0);
        acc[m][j] = __builtin_amdgcn_mfma_f32_16x16x32_f16(a[m], wl, acc[m][j], 0, 0, 0);
      }
    }
  }
  float atv[2], adv[2];
  #pragma unroll
  for (int j=0;j<2;++j){ atv[j] = atts[wcol+j*16+r]; adv[j] = attd[wcol+j*16+r]; }
  #pragma unroll
  for (int m=0;m<4;++m){
    float ps[4] = {0,0,0,0};   // [q] — single head per wave
    float pd[4] = {0,0,0,0};
    #pragma unroll
    for (int j=0;j<2;++j){
      const int c = wcol + j*16 + r;
      #pragma unroll
      for (int q=0;q<4;++q){
        const int row = row0 + m*16 + g*4 + q;
        const float v = acc[m][j][q];
        if (row < NN) Cout[(size_t)row*HID + c] = (f16)v;
        ps[q] = fmaf(v, atv[j], ps[q]);
        pd[q] = fmaf(v, adv[j], pd[q]);
      }
    }
    #pragma unroll
    for (int q=0;q<4;++q){
      float s = ps[q], d = pd[q];
      s += __shfl_xor(s,1); s += __shfl_xor(s,2); s += __shfl_xor(s,4); s += __shfl_xor(s,8);
      d += __shfl_xor(d,1); d += __shfl_xor(d,2); d += __shfl_xor(d,4); d += __shfl_xor(d,8);
      if (r == 0){
        const int row = row0 + m*16 + g*4 + q;
        if (row < NN){
          a_src[(size_t)row*NH + head] = s;
          a_dst[(size_t)row*NH + head] = d;
        }
      }
    }
  }
}

// ---------------- layer-1 agg: wave/node, 256-dim f16 gather, +bias+gelu ----------------
__global__ __launch_bounds__(256) void k_aggH(const f16* __restrict__ feat,
    const u16s* __restrict__ col, const u32* __restrict__ start, const u32* __restrict__ cnt,
    const float* __restrict__ nrmE, const float* __restrict__ bias, f16* __restrict__ out){
  const int n = (int)((blockIdx.x*blockDim.x + threadIdx.x) >> 6);
  if (n >= NN) return;
  const int lane = threadIdx.x & 63;
  const u32 b = start[n], e = b + cnt[n];
  const int fo = lane*4;
  float a0=0.f,a1=0.f,a2=0.f,a3=0.f;
  u32 s0 = col[b];
  float w0 = nrmE[b];
  f16x4 v0 = *(const f16x4*)(feat + (size_t)s0*HID + fo);
  for (u32 k=b+1; k<e; ++k){
    const u32 s1 = col[k];
    const float w1 = nrmE[k];
    const f16x4 v1 = *(const f16x4*)(feat + (size_t)s1*HID + fo);
    a0 = fmaf(w0, (float)v0.x, a0);
    a1 = fmaf(w0, (float)v0.y, a1);
    a2 = fmaf(w0, (float)v0.z, a2);
    a3 = fmaf(w0, (float)v0.w, a3);
    v0 = v1; w0 = w1;
  }
  a0 = fmaf(w0, (float)v0.x, a0);
  a1 = fmaf(w0, (float)v0.y, a1);
  a2 = fmaf(w0, (float)v0.z, a2);
  a3 = fmaf(w0, (float)v0.w, a3);
  const float4 bv = *(const float4*)(bias + fo);
  f16x4 o;
  o.x = (f16)geluf(a0 + bv.x);
  o.y = (f16)geluf(a1 + bv.y);
  o.z = (f16)geluf(a2 + bv.z);
  o.w = (f16)geluf(a3 + bv.w);
  *(f16x4*)(out + (size_t)n*HID + fo) = o;
}

// ---------------- fused GAT: single-pass softmax-free weighted gather + bias + relu ----------------
// out = (sum_k exp(e_k) v_k) / (sum_k exp(e_k)); e_k ~O(5) so unshifted exp is safe.
__global__ __launch_bounds__(256) void k_gat_fused(const f16* __restrict__ gfeat,
    const u16s* __restrict__ col, const u32* __restrict__ start, const u32* __restrict__ cnt,
    const float* __restrict__ a_src, const float* __restrict__ a_dst,
    const float* __restrict__ b_att, f16* __restrict__ h2){
  const int n = (int)((blockIdx.x*blockDim.x + threadIdx.x) >> 6);
  if (n >= NN) return;
  const int lane = threadIdx.x & 63;
  const int head = lane >> 3;            // feats [32h,32h+32) <-> lanes [8h,8h+8)
  const int fo = lane*4;
  const u32 b = start[n], e = b + cnt[n];
  const float ad = a_dst[(size_t)n*NH + head];
  float a0=0.f,a1=0.f,a2=0.f,a3=0.f,sp=0.f;
  u32 s0 = col[b];
  float as0 = a_src[(size_t)s0*NH + head];
  f16x4 v0 = *(const f16x4*)(gfeat + (size_t)s0*HID + fo);
  for (u32 k=b+1; k<e; ++k){
    const u32 s1 = col[k];
    const float as1 = a_src[(size_t)s1*NH + head];
    const f16x4 v1 = *(const f16x4*)(gfeat + (size_t)s1*HID + fo);
    const float p = expf(leakyf(as0 + ad));
    sp += p;
    a0 = fmaf(p, (float)v0.x, a0);
    a1 = fmaf(p, (float)v0.y, a1);
    a2 = fmaf(p, (float)v0.z, a2);
    a3 = fmaf(p, (float)v0.w, a3);
    v0 = v1; as0 = as1;
  }
  const float p = expf(leakyf(as0 + ad));
  sp += p;
  a0 = fmaf(p, (float)v0.x, a0);
  a1 = fmaf(p, (float)v0.y, a1);
  a2 = fmaf(p, (float)v0.z, a2);
  a3 = fmaf(p, (float)v0.w, a3);
  const float inv_s = 1.f / sp;
  const float4 bv = *(const float4*)(b_att + fo);
  f16x4 o;
  o.x = (f16)fmaxf(fmaf(a0, inv_s, bv.x), 0.f);
  o.y = (f16)fmaxf(fmaf(a1, inv_s, bv.y), 0.f);
  o.z = (f16)fmaxf(fmaf(a2, inv_s, bv.z), 0.f);
  o.w = (f16)fmaxf(fmaf(a3, inv_s, bv.w), 0.f);
  *(f16x4*)(h2 + (size_t)n*HID + fo) = o;
}

// ---------------- layer-3 agg: 128-dim, 4 edges/iter, 16B loads, f32 out (mu | logstd) ----------------
__global__ __launch_bounds__(256) void k_agg_out(const f16* __restrict__ p,
    const u16s* __restrict__ col, const u32* __restrict__ start, const u32* __restrict__ cnt,
    const float* __restrict__ nrmE, const float* __restrict__ b_mu, const float* __restrict__ b_ls,
    float* __restrict__ out){
  const int n = (int)((blockIdx.x*blockDim.x + threadIdx.x) >> 6);
  if (n >= NN) return;
  const int lane = threadIdx.x & 63;
  const int q4 = lane >> 4, l4 = lane & 15;
  const int fo = l4*8;                 // 8 f16 = 16 B per lane (128-dim row)
  const u32 b = start[n], c = cnt[n];
  float acc[8] = {0.f,0.f,0.f,0.f,0.f,0.f,0.f,0.f};
  u32 i0 = (u32)q4;
  bool v0 = i0 < c;
  u32 idx0 = b + (v0 ? i0 : 0u);
  u32 s0 = col[idx0];
  float nrm0 = v0 ? nrmE[idx0] : 0.f;
  f16x8 f0 = *(const f16x8*)(p + (size_t)s0*PC + fo);
  for (u32 k=4; k<c; k+=4){
    const u32 i1 = k + (u32)q4;
    const bool v1 = i1 < c;
    const u32 idx1 = b + (v1 ? i1 : 0u);
    const u32 s1 = col[idx1];
    const float nrm1 = v1 ? nrmE[idx1] : 0.f;
    const f16x8 f1 = *(const f16x8*)(p + (size_t)s1*PC + fo);
    #pragma unroll
    for (int j=0;j<8;++j) acc[j] = fmaf(nrm0, (float)f0[j], acc[j]);
    f0 = f1; nrm0 = nrm1;
  }
  #pragma unroll
  for (int j=0;j<8;++j) acc[j] = fmaf(nrm0, (float)f0[j], acc[j]);
  #pragma unroll
  for (int j=0;j<8;++j){
    acc[j] += __shfl_xor(acc[j], 16);
    acc[j] += __shfl_xor(acc[j], 32);
  }
  if (q4 == 0){
    if (l4 < 8){
      const int cc = fo;               // mu cols 0..63
      float4 o0 = make_float4(acc[0]+b_mu[cc], acc[1]+b_mu[cc+1], acc[2]+b_mu[cc+2], acc[3]+b_mu[cc+3]);
      float4 o1 = make_float4(acc[4]+b_mu[cc+4], acc[5]+b_mu[cc+5], acc[6]+b_mu[cc+6], acc[7]+b_mu[cc+7]);
      *(float4*)(out + (size_t)n*OC + cc) = o0;
      *(float4*)(out + (size_t)n*OC + cc + 4) = o1;
    } else {
      const int cc = fo - OC;          // logstd cols 0..63
      float* o = out + (size_t)NN*OC + (size_t)n*OC + cc;
      float4 o0 = make_float4(acc[0]+b_ls[cc], acc[1]+b_ls[cc+1], acc[2]+b_ls[cc+2], acc[3]+b_ls[cc+3]);
      float4 o1 = make_float4(acc[4]+b_ls[cc+4], acc[5]+b_ls[cc+5], acc[6]+b_ls[cc+6], acc[7]+b_ls[cc+7]);
      *(float4*)o = o0;
      *(float4*)(o + 4) = o1;
    }
  }
}

extern "C" void kernel_launch(void* const* d_in, const int* in_sizes, int n_in,
                              void* d_out, int out_size, void* d_ws, size_t ws_size,
                              hipStream_t stream){
  const float* x    = (const float*)d_in[0];
  const int*   ei   = (const int*)d_in[1];
  const float* w1   = (const float*)d_in[2];
  const float* b1   = (const float*)d_in[3];
  const float* watt = (const float*)d_in[4];
  const float* atts = (const float*)d_in[5];
  const float* attd = (const float*)d_in[6];
  const float* batt = (const float*)d_in[7];
  const float* wmu  = (const float*)d_in[8];
  const float* bmu  = (const float*)d_in[9];
  const float* wls  = (const float*)d_in[10];
  const float* bls  = (const float*)d_in[11];
  const int* esrc = ei;
  const int* edst = ei + EE;

  char* p = (char*)d_ws;
  f16* bufA = (f16*)p;  p += (size_t)NN*HID*2;   // 25.6 MB: g1 (x@w1) -> h2
  f16* bufB = (f16*)p;  p += (size_t)NN*HID*2;   // 25.6 MB: h1 -> proj(128)
  f16* bufC = (f16*)p;  p += (size_t)NN*HID*2;   // 25.6 MB: g (GAT feats)
  float* nrmE = (float*)p; p += (size_t)ET*4;    // 3.4 MB per-edge GCN norm
  f16* w1h   = (f16*)p;  p += (size_t)HID*HID*2;
  f16* w1l   = (f16*)p;  p += (size_t)HID*HID*2;
  f16* wahi  = (f16*)p;  p += (size_t)HID*HID*2;
  f16* walo  = (f16*)p;  p += (size_t)HID*HID*2;
  f16* wchi  = (f16*)p;  p += (size_t)PC*HID*2;
  f16* wclo  = (f16*)p;  p += (size_t)PC*HID*2;
  float* dinv = (float*)p; p += (size_t)NN*4;
  float* asr  = (float*)p; p += (size_t)NN*NH*4;
  float* ads  = (float*)p; p += (size_t)NN*NH*4;
  u32*   cnt  = (u32*)p;   p += (size_t)NN*4;
  u32*   start= (u32*)p;   p += (size_t)NN*4;
  u32*   pos  = (u32*)p;   p += (size_t)NN*4;
  u32*   counter = (u32*)p; p += 256;
  u16s*  colU = (u16s*)p;  p += (size_t)ET*2;    // 1.7 MB

  const int TB = 256;
  // CSR build (memset replaces k_init; self-loop folded into k_alloc)
  hipMemsetAsync(cnt, 0, (size_t)NN*4, stream);
  hipMemsetAsync(counter, 0, 4, stream);
  k_count<<<(EE+TB-1)/TB, TB, 0, stream>>>(edst, cnt);
  k_alloc<<<(NN+TB-1)/TB, TB, 0, stream>>>(cnt, counter, start, pos, dinv);
  k_fill <<<(ET+TB-1)/TB, TB, 0, stream>>>(esrc, edst, pos, colU, dinv, nrmE);
  // weight splits (single launch)
  k_wsplit_all<<<(2*W1N + 2*OC*HID + TB-1)/TB, TB, 0, stream>>>(
      w1, watt, wmu, wls, w1h, w1l, wahi, walo, wchi, wclo);

  const int NWB = NN/4;             // wave-per-node kernels (4 waves/block)
  const int G64 = (NN + 63)/64;     // 64-row blocks
  // layer 1: g1 = x@w1 (f32 A in-reg convert, MR=4, col-split 2) ; h1 = gelu(agg(g1)+b1)
  k_gemm_fx<HID,2,4,2><<<G64*2, TB, 0, stream>>>(x, w1h, w1l, bufA);
  k_aggH<<<NWB, TB, 0, stream>>>(bufA, colU, start, cnt, nrmE, b1, bufB);
  // GAT: g = h1@w_att (+fused att coefs, col-split 2) ; single-pass softmax-free aggregate
  k_gemm_att<<<G64*2, TB, 0, stream>>>(bufB, wahi, walo, atts, attd, bufC, asr, ads);
  k_gat_fused<<<NWB, TB, 0, stream>>>(bufC, colU, start, cnt, asr, ads, batt, bufA);
  // layer 3: project (128 cols = mu||ls, col-split 2), then one 128-dim gather -> d_out
  k_gemm_f16A<PC,1,4,2><<<G64*2, TB, 0, stream>>>(bufA, wchi, wclo, bufB);
  k_agg_out<<<NWB, TB, 0, stream>>>(bufB, colU, start, cnt, nrmE, bmu, bls, (float*)d_out);
}

// Round 16
// 445.567 us; speedup vs baseline: 1.0578x; 1.0578x over previous
//
#include <hip/hip_runtime.h>

#define NN 50000
#define EE 800000
#define ET (EE + NN)
#define HID 256
#define NH 8
#define HC 32
#define OC 64
#define PC 128   // layer-3 projected width (mu||logstd)

typedef unsigned int u32;
typedef unsigned short u16s;
typedef _Float16 f16;
typedef __attribute__((ext_vector_type(8))) _Float16 f16x8;
typedef __attribute__((ext_vector_type(4))) _Float16 f16x4;
typedef __attribute__((ext_vector_type(4))) float f32x4;

static __device__ __forceinline__ float geluf(float x){
  float t = tanhf(0.7978845608028654f*(x + 0.044715f*x*x*x));
  return 0.5f*x*(1.0f+t);
}
static __device__ __forceinline__ float leakyf(float x){
  return x > 0.0f ? x : 0.2f*x;
}

// ---------------- CSR build ----------------
__global__ void k_count(const int* __restrict__ dst, u32* __restrict__ cnt){
  int e = blockIdx.x*blockDim.x + threadIdx.x;
  if (e < EE) atomicAdd(&cnt[dst[e]], 1u);
}
// wave-aggregated bump allocation: 1 atomic per wave (G12). Adds self-loop (+1).
__global__ void k_alloc(u32* __restrict__ cnt, u32* counter,
                        u32* __restrict__ start, u32* __restrict__ pos,
                        float* __restrict__ dinv){
  int n = blockIdx.x*blockDim.x + threadIdx.x;
  const int lane = threadIdx.x & 63;
  u32 c = (n < NN) ? (cnt[n] + 1u) : 0u;   // +1 self loop
  u32 pre = c;                          // wave-inclusive prefix sum
  #pragma unroll
  for (int off=1; off<64; off<<=1){
    u32 v = __shfl_up(pre, off);
    if (lane >= off) pre += v;
  }
  u32 tot = __shfl(pre, 63);
  u32 base = 0;
  if (lane == 63) base = atomicAdd(counter, tot);
  base = __shfl(base, 63);
  if (n < NN){
    u32 s = base + pre - c;             // exclusive
    start[n] = s; pos[n] = s;
    dinv[n] = rsqrtf((float)c);
    cnt[n] = c;                         // store total (incl self loop)
  }
}
__global__ void k_fill(const int* __restrict__ src, const int* __restrict__ dst,
                       u32* __restrict__ pos, u16s* __restrict__ col,
                       const float* __restrict__ dinv, float* __restrict__ nrmE){
  int e = blockIdx.x*blockDim.x + threadIdx.x;
  if (e < ET){
    int s, d;
    if (e < EE){ s = src[e]; d = dst[e]; } else { s = d = e - EE; }
    u32 idx = atomicAdd(&pos[d], 1u);
    col[idx] = (u16s)s;
    nrmE[idx] = dinv[s] * dinv[d];
  }
}

// ---------------- x -> f16 (streaming) ----------------
__global__ void k_x16(const float* __restrict__ x, f16* __restrict__ o){
  int i = blockIdx.x*blockDim.x + threadIdx.x;
  if (i >= NN*HID/8) return;
  const float4 u0 = *(const float4*)(x + (size_t)i*8);
  const float4 u1 = *(const float4*)(x + (size_t)i*8 + 4);
  f16x8 v;
  v[0]=(f16)u0.x; v[1]=(f16)u0.y; v[2]=(f16)u0.z; v[3]=(f16)u0.w;
  v[4]=(f16)u1.x; v[5]=(f16)u1.y; v[6]=(f16)u1.z; v[7]=(f16)u1.w;
  *(f16x8*)(o + (size_t)i*8) = v;
}

// ---------------- all weight splits in one kernel ----------------
// W[K=256][NC] f32 row-major -> hi/lo f16 col-major
#define W1N (HID*HID)
__global__ void k_wsplit_all(const float* __restrict__ w1, const float* __restrict__ watt,
    const float* __restrict__ wmu, const float* __restrict__ wls,
    f16* __restrict__ w1h, f16* __restrict__ w1l,
    f16* __restrict__ wah, f16* __restrict__ wal,
    f16* __restrict__ wch, f16* __restrict__ wcl){
  int e = blockIdx.x*blockDim.x + threadIdx.x;
  const float* W; f16 *H, *L; int NC, coff = 0, idx;
  if (e < W1N){ W=w1; H=w1h; L=w1l; NC=HID; idx=e; }
  else if (e < 2*W1N){ W=watt; H=wah; L=wal; NC=HID; idx=e-W1N; }
  else if (e < 2*W1N + OC*HID){ W=wmu; H=wch; L=wcl; NC=OC; idx=e-2*W1N; }
  else if (e < 2*W1N + 2*OC*HID){ W=wls; H=wch; L=wcl; NC=OC; coff=OC; idx=e-2*W1N-OC*HID; }
  else return;
  int c = idx / HID, k = idx % HID;
  float w = W[(size_t)k*NC + c];
  f16 hi = (f16)w;
  f16 lo = (f16)(w - (float)hi);
  H[(size_t)(c+coff)*HID + k] = hi;
  L[(size_t)(c+coff)*HID + k] = lo;
}

// ---------------- GEMM (f16 A, 2-pass f16 W split, MR=4) ----------------
template<int NC, int NF, int MR>
__global__ __launch_bounds__(256) void k_gemm_f16A(const f16* __restrict__ A,
    const f16* __restrict__ Whi, const f16* __restrict__ Wlo, f16* __restrict__ Cout){
  const int tid = threadIdx.x;
  const int w = tid >> 6, lane = tid & 63;
  const int r = lane & 15, g = lane >> 4;
  const int row0 = blockIdx.x * (MR*16);
  const int wcol = w * (NF*16);
  f32x4 acc[MR][NF];
  #pragma unroll
  for (int m=0;m<MR;++m)
    #pragma unroll
    for (int j=0;j<NF;++j){ f32x4 z = {0.f,0.f,0.f,0.f}; acc[m][j] = z; }
  #pragma unroll
  for (int kk=0; kk<8; ++kk){
    const int k0 = kk*32 + g*8;
    f16x8 a[MR];
    #pragma unroll
    for (int m=0;m<MR;++m){
      const int row = row0 + m*16 + r;
      f16x8 z = {0,0,0,0,0,0,0,0};
      a[m] = (row < NN) ? *(const f16x8*)(A + (size_t)row*HID + k0) : z;
    }
    #pragma unroll
    for (int j=0;j<NF;++j){
      const int c = wcol + j*16 + r;
      const size_t off = (size_t)c*HID + k0;
      const f16x8 wh = *(const f16x8*)(Whi + off);
      const f16x8 wl = *(const f16x8*)(Wlo + off);
      #pragma unroll
      for (int m=0;m<MR;++m){
        acc[m][j] = __builtin_amdgcn_mfma_f32_16x16x32_f16(a[m], wh, acc[m][j], 0, 0, 0);
        acc[m][j] = __builtin_amdgcn_mfma_f32_16x16x32_f16(a[m], wl, acc[m][j], 0, 0, 0);
      }
    }
  }
  #pragma unroll
  for (int j=0;j<NF;++j){
    const int c = wcol + j*16 + r;
    #pragma unroll
    for (int m=0;m<MR;++m){
      #pragma unroll
      for (int q=0;q<4;++q){
        const int row = row0 + m*16 + g*4 + q;
        if (row < NN) Cout[(size_t)row*NC + c] = (f16)acc[m][j][q];
      }
    }
  }
}

// ---------------- GAT GEMM (f16 A) + fused attention coefficients ----------------
// Wave w covers cols [64w,64w+64) == heads {2w, 2w+1}; per-head attention dots
// reduce within the wave (shuffle over r-lanes), no LDS.
__global__ __launch_bounds__(256) void k_gemm_att(const f16* __restrict__ A,
    const f16* __restrict__ Whi, const f16* __restrict__ Wlo,
    const float* __restrict__ atts, const float* __restrict__ attd,
    f16* __restrict__ Cout, float* __restrict__ a_src, float* __restrict__ a_dst){
  const int tid = threadIdx.x;
  const int w = tid >> 6, lane = tid & 63;
  const int r = lane & 15, g = lane >> 4;
  const int row0 = blockIdx.x * 64;
  const int wcol = w * 64;
  f32x4 acc[4][4];
  #pragma unroll
  for (int m=0;m<4;++m)
    #pragma unroll
    for (int j=0;j<4;++j){ f32x4 z = {0.f,0.f,0.f,0.f}; acc[m][j] = z; }
  #pragma unroll
  for (int kk=0; kk<8; ++kk){
    const int k0 = kk*32 + g*8;
    f16x8 a[4];
    #pragma unroll
    for (int m=0;m<4;++m){
      const int row = row0 + m*16 + r;
      f16x8 z = {0,0,0,0,0,0,0,0};
      a[m] = (row < NN) ? *(const f16x8*)(A + (size_t)row*HID + k0) : z;
    }
    #pragma unroll
    for (int j=0;j<4;++j){
      const int c = wcol + j*16 + r;
      const size_t off = (size_t)c*HID + k0;
      const f16x8 wh = *(const f16x8*)(Whi + off);
      const f16x8 wl = *(const f16x8*)(Wlo + off);
      #pragma unroll
      for (int m=0;m<4;++m){
        acc[m][j] = __builtin_amdgcn_mfma_f32_16x16x32_f16(a[m], wh, acc[m][j], 0, 0, 0);
        acc[m][j] = __builtin_amdgcn_mfma_f32_16x16x32_f16(a[m], wl, acc[m][j], 0, 0, 0);
      }
    }
  }
  float atv[4], adv[4];
  #pragma unroll
  for (int j=0;j<4;++j){ atv[j] = atts[wcol+j*16+r]; adv[j] = attd[wcol+j*16+r]; }
  #pragma unroll
  for (int m=0;m<4;++m){
    float ps[2][4] = {{0,0,0,0},{0,0,0,0}};   // [head_local][q]
    float pd[2][4] = {{0,0,0,0},{0,0,0,0}};
    #pragma unroll
    for (int j=0;j<4;++j){
      const int c = wcol + j*16 + r;
      const int hl = j >> 1;
      #pragma unroll
      for (int q=0;q<4;++q){
        const int row = row0 + m*16 + g*4 + q;
        const float v = acc[m][j][q];
        if (row < NN) Cout[(size_t)row*HID + c] = (f16)v;
        ps[hl][q] = fmaf(v, atv[j], ps[hl][q]);
        pd[hl][q] = fmaf(v, adv[j], pd[hl][q]);
      }
    }
    #pragma unroll
    for (int hl=0;hl<2;++hl)
      #pragma unroll
      for (int q=0;q<4;++q){
        float s = ps[hl][q], d = pd[hl][q];
        s += __shfl_xor(s,1); s += __shfl_xor(s,2); s += __shfl_xor(s,4); s += __shfl_xor(s,8);
        d += __shfl_xor(d,1); d += __shfl_xor(d,2); d += __shfl_xor(d,4); d += __shfl_xor(d,8);
        if (r == 0){
          const int row = row0 + m*16 + g*4 + q;
          if (row < NN){
            a_src[(size_t)row*NH + 2*w + hl] = s;
            a_dst[(size_t)row*NH + 2*w + hl] = d;
          }
        }
      }
  }
}

// ---------------- layer-1 agg: wave/node, 256-dim f16 gather, +bias+gelu ----------------
__global__ __launch_bounds__(256) void k_aggH(const f16* __restrict__ feat,
    const u16s* __restrict__ col, const u32* __restrict__ start, const u32* __restrict__ cnt,
    const float* __restrict__ nrmE, const float* __restrict__ bias, f16* __restrict__ out){
  const int n = (int)((blockIdx.x*blockDim.x + threadIdx.x) >> 6);
  if (n >= NN) return;
  const int lane = threadIdx.x & 63;
  const u32 b = start[n], e = b + cnt[n];
  const int fo = lane*4;
  float a0=0.f,a1=0.f,a2=0.f,a3=0.f;
  u32 s0 = col[b];
  float w0 = nrmE[b];
  f16x4 v0 = *(const f16x4*)(feat + (size_t)s0*HID + fo);
  for (u32 k=b+1; k<e; ++k){
    const u32 s1 = col[k];
    const float w1 = nrmE[k];
    const f16x4 v1 = *(const f16x4*)(feat + (size_t)s1*HID + fo);
    a0 = fmaf(w0, (float)v0.x, a0);
    a1 = fmaf(w0, (float)v0.y, a1);
    a2 = fmaf(w0, (float)v0.z, a2);
    a3 = fmaf(w0, (float)v0.w, a3);
    v0 = v1; w0 = w1;
  }
  a0 = fmaf(w0, (float)v0.x, a0);
  a1 = fmaf(w0, (float)v0.y, a1);
  a2 = fmaf(w0, (float)v0.z, a2);
  a3 = fmaf(w0, (float)v0.w, a3);
  const float4 bv = *(const float4*)(bias + fo);
  f16x4 o;
  o.x = (f16)geluf(a0 + bv.x);
  o.y = (f16)geluf(a1 + bv.y);
  o.z = (f16)geluf(a2 + bv.z);
  o.w = (f16)geluf(a3 + bv.w);
  *(f16x4*)(out + (size_t)n*HID + fo) = o;
}

// ---------------- fused GAT: single-pass softmax-free weighted gather + bias + relu ----------------
// out = (sum_k exp(e_k) v_k) / (sum_k exp(e_k)); e_k ~O(5) so unshifted exp is safe.
__global__ __launch_bounds__(256) void k_gat_fused(const f16* __restrict__ gfeat,
    const u16s* __restrict__ col, const u32* __restrict__ start, const u32* __restrict__ cnt,
    const float* __restrict__ a_src, const float* __restrict__ a_dst,
    const float* __restrict__ b_att, f16* __restrict__ h2){
  const int n = (int)((blockIdx.x*blockDim.x + threadIdx.x) >> 6);
  if (n >= NN) return;
  const int lane = threadIdx.x & 63;
  const int head = lane >> 3;            // feats [32h,32h+32) <-> lanes [8h,8h+8)
  const int fo = lane*4;
  const u32 b = start[n], e = b + cnt[n];
  const float ad = a_dst[(size_t)n*NH + head];
  float a0=0.f,a1=0.f,a2=0.f,a3=0.f,sp=0.f;
  u32 s0 = col[b];
  float as0 = a_src[(size_t)s0*NH + head];
  f16x4 v0 = *(const f16x4*)(gfeat + (size_t)s0*HID + fo);
  for (u32 k=b+1; k<e; ++k){
    const u32 s1 = col[k];
    const float as1 = a_src[(size_t)s1*NH + head];
    const f16x4 v1 = *(const f16x4*)(gfeat + (size_t)s1*HID + fo);
    const float p = expf(leakyf(as0 + ad));
    sp += p;
    a0 = fmaf(p, (float)v0.x, a0);
    a1 = fmaf(p, (float)v0.y, a1);
    a2 = fmaf(p, (float)v0.z, a2);
    a3 = fmaf(p, (float)v0.w, a3);
    v0 = v1; as0 = as1;
  }
  const float p = expf(leakyf(as0 + ad));
  sp += p;
  a0 = fmaf(p, (float)v0.x, a0);
  a1 = fmaf(p, (float)v0.y, a1);
  a2 = fmaf(p, (float)v0.z, a2);
  a3 = fmaf(p, (float)v0.w, a3);
  const float inv_s = 1.f / sp;
  const float4 bv = *(const float4*)(b_att + fo);
  f16x4 o;
  o.x = (f16)fmaxf(fmaf(a0, inv_s, bv.x), 0.f);
  o.y = (f16)fmaxf(fmaf(a1, inv_s, bv.y), 0.f);
  o.z = (f16)fmaxf(fmaf(a2, inv_s, bv.z), 0.f);
  o.w = (f16)fmaxf(fmaf(a3, inv_s, bv.w), 0.f);
  *(f16x4*)(h2 + (size_t)n*HID + fo) = o;
}

// ---------------- layer-3 agg: 128-dim, 4 edges/iter, 16B loads, f32 out (mu | logstd) ----------------
__global__ __launch_bounds__(256) void k_agg_out(const f16* __restrict__ p,
    const u16s* __restrict__ col, const u32* __restrict__ start, const u32* __restrict__ cnt,
    const float* __restrict__ nrmE, const float* __restrict__ b_mu, const float* __restrict__ b_ls,
    float* __restrict__ out){
  const int n = (int)((blockIdx.x*blockDim.x + threadIdx.x) >> 6);
  if (n >= NN) return;
  const int lane = threadIdx.x & 63;
  const int q4 = lane >> 4, l4 = lane & 15;
  const int fo = l4*8;                 // 8 f16 = 16 B per lane (128-dim row)
  const u32 b = start[n], c = cnt[n];
  float acc[8] = {0.f,0.f,0.f,0.f,0.f,0.f,0.f,0.f};
  u32 i0 = (u32)q4;
  bool v0 = i0 < c;
  u32 idx0 = b + (v0 ? i0 : 0u);
  u32 s0 = col[idx0];
  float nrm0 = v0 ? nrmE[idx0] : 0.f;
  f16x8 f0 = *(const f16x8*)(p + (size_t)s0*PC + fo);
  for (u32 k=4; k<c; k+=4){
    const u32 i1 = k + (u32)q4;
    const bool v1 = i1 < c;
    const u32 idx1 = b + (v1 ? i1 : 0u);
    const u32 s1 = col[idx1];
    const float nrm1 = v1 ? nrmE[idx1] : 0.f;
    const f16x8 f1 = *(const f16x8*)(p + (size_t)s1*PC + fo);
    #pragma unroll
    for (int j=0;j<8;++j) acc[j] = fmaf(nrm0, (float)f0[j], acc[j]);
    f0 = f1; nrm0 = nrm1;
  }
  #pragma unroll
  for (int j=0;j<8;++j) acc[j] = fmaf(nrm0, (float)f0[j], acc[j]);
  #pragma unroll
  for (int j=0;j<8;++j){
    acc[j] += __shfl_xor(acc[j], 16);
    acc[j] += __shfl_xor(acc[j], 32);
  }
  if (q4 == 0){
    if (l4 < 8){
      const int cc = fo;               // mu cols 0..63
      float4 o0 = make_float4(acc[0]+b_mu[cc], acc[1]+b_mu[cc+1], acc[2]+b_mu[cc+2], acc[3]+b_mu[cc+3]);
      float4 o1 = make_float4(acc[4]+b_mu[cc+4], acc[5]+b_mu[cc+5], acc[6]+b_mu[cc+6], acc[7]+b_mu[cc+7]);
      *(float4*)(out + (size_t)n*OC + cc) = o0;
      *(float4*)(out + (size_t)n*OC + cc + 4) = o1;
    } else {
      const int cc = fo - OC;          // logstd cols 0..63
      float* o = out + (size_t)NN*OC + (size_t)n*OC + cc;
      float4 o0 = make_float4(acc[0]+b_ls[cc], acc[1]+b_ls[cc+1], acc[2]+b_ls[cc+2], acc[3]+b_ls[cc+3]);
      float4 o1 = make_float4(acc[4]+b_ls[cc+4], acc[5]+b_ls[cc+5], acc[6]+b_ls[cc+6], acc[7]+b_ls[cc+7]);
      *(float4*)o = o0;
      *(float4*)(o + 4) = o1;
    }
  }
}

extern "C" void kernel_launch(void* const* d_in, const int* in_sizes, int n_in,
                              void* d_out, int out_size, void* d_ws, size_t ws_size,
                              hipStream_t stream){
  const float* x    = (const float*)d_in[0];
  const int*   ei   = (const int*)d_in[1];
  const float* w1   = (const float*)d_in[2];
  const float* b1   = (const float*)d_in[3];
  const float* watt = (const float*)d_in[4];
  const float* atts = (const float*)d_in[5];
  const float* attd = (const float*)d_in[6];
  const float* batt = (const float*)d_in[7];
  const float* wmu  = (const float*)d_in[8];
  const float* bmu  = (const float*)d_in[9];
  const float* wls  = (const float*)d_in[10];
  const float* bls  = (const float*)d_in[11];
  const int* esrc = ei;
  const int* edst = ei + EE;

  char* p = (char*)d_ws;
  f16* bufA = (f16*)p;  p += (size_t)NN*HID*2;   // 25.6 MB: g1 (x16@w1) -> h2
  f16* bufB = (f16*)p;  p += (size_t)NN*HID*2;   // 25.6 MB: h1 -> proj(128)
  f16* bufC = (f16*)p;  p += (size_t)NN*HID*2;   // 25.6 MB: x16 -> g (GAT feats)
  float* nrmE = (float*)p; p += (size_t)ET*4;    // 3.4 MB per-edge GCN norm
  f16* w1h   = (f16*)p;  p += (size_t)HID*HID*2;
  f16* w1l   = (f16*)p;  p += (size_t)HID*HID*2;
  f16* wahi  = (f16*)p;  p += (size_t)HID*HID*2;
  f16* walo  = (f16*)p;  p += (size_t)HID*HID*2;
  f16* wchi  = (f16*)p;  p += (size_t)PC*HID*2;
  f16* wclo  = (f16*)p;  p += (size_t)PC*HID*2;
  float* dinv = (float*)p; p += (size_t)NN*4;
  float* asr  = (float*)p; p += (size_t)NN*NH*4;
  float* ads  = (float*)p; p += (size_t)NN*NH*4;
  u32*   cnt  = (u32*)p;   p += (size_t)NN*4;
  u32*   start= (u32*)p;   p += (size_t)NN*4;
  u32*   pos  = (u32*)p;   p += (size_t)NN*4;
  u32*   counter = (u32*)p; p += 256;
  u16s*  colU = (u16s*)p;  p += (size_t)ET*2;    // 1.7 MB

  const int TB = 256;
  // CSR build (memset init; self-loop folded into k_alloc)
  hipMemsetAsync(cnt, 0, (size_t)NN*4, stream);
  hipMemsetAsync(counter, 0, 4, stream);
  k_count<<<(EE+TB-1)/TB, TB, 0, stream>>>(edst, cnt);
  k_alloc<<<(NN+TB-1)/TB, TB, 0, stream>>>(cnt, counter, start, pos, dinv);
  k_fill <<<(ET+TB-1)/TB, TB, 0, stream>>>(esrc, edst, pos, colU, dinv, nrmE);
  // weight splits (single launch) + x -> f16
  k_wsplit_all<<<(2*W1N + 2*OC*HID + TB-1)/TB, TB, 0, stream>>>(
      w1, watt, wmu, wls, w1h, w1l, wahi, walo, wchi, wclo);
  k_x16<<<(NN*HID/8 + TB-1)/TB, TB, 0, stream>>>(x, bufC);

  const int NWB = NN/4;             // wave-per-node kernels (4 waves/block)
  const int G64 = (NN + 63)/64;     // 64-row GEMM blocks
  // layer 1: g1 = x16@w1 ; h1 = gelu(agg(g1) + b1)
  k_gemm_f16A<HID,4,4><<<G64, TB, 0, stream>>>(bufC, w1h, w1l, bufA);
  k_aggH<<<NWB, TB, 0, stream>>>(bufA, colU, start, cnt, nrmE, b1, bufB);
  // GAT: g = h1@w_att (+fused att coefs) ; single-pass softmax-free aggregate
  k_gemm_att<<<G64, TB, 0, stream>>>(bufB, wahi, walo, atts, attd, bufC, asr, ads);
  k_gat_fused<<<NWB, TB, 0, stream>>>(bufC, colU, start, cnt, asr, ads, batt, bufA);
  // layer 3: project first (128 cols = mu||ls), then one 128-dim gather -> d_out
  k_gemm_f16A<PC,2,4><<<G64, TB, 0, stream>>>(bufA, wchi, wclo, bufB);
  k_agg_out<<<NWB, TB, 0, stream>>>(bufB, colU, start, cnt, nrmE, bmu, bls, (float*)d_out);
}

// Round 17
// 403.657 us; speedup vs baseline: 1.1677x; 1.1038x over previous
//
#include <hip/hip_runtime.h>

#define NN 50000
#define EE 800000
#define ET (EE + NN)
#define HID 256
#define NH 8
#define HC 32
#define OC 64
#define PC 128   // layer-3 projected width (mu||logstd)

typedef unsigned int u32;
typedef unsigned short u16s;
typedef _Float16 f16;
typedef __attribute__((ext_vector_type(8))) _Float16 f16x8;
typedef __attribute__((ext_vector_type(4))) _Float16 f16x4;
typedef __attribute__((ext_vector_type(4))) float f32x4;

static __device__ __forceinline__ float geluf(float x){
  float t = tanhf(0.7978845608028654f*(x + 0.044715f*x*x*x));
  return 0.5f*x*(1.0f+t);
}
static __device__ __forceinline__ float leakyf(float x){
  return x > 0.0f ? x : 0.2f*x;
}

// ---------------- CSR build ----------------
__global__ void k_count(const int* __restrict__ dst, u32* __restrict__ cnt){
  int e = blockIdx.x*blockDim.x + threadIdx.x;
  if (e < EE) atomicAdd(&cnt[dst[e]], 1u);
}
// wave-aggregated bump allocation: 1 atomic per wave (G12). Adds self-loop (+1).
__global__ void k_alloc(u32* __restrict__ cnt, u32* counter,
                        u32* __restrict__ start, u32* __restrict__ pos,
                        float* __restrict__ dinv){
  int n = blockIdx.x*blockDim.x + threadIdx.x;
  const int lane = threadIdx.x & 63;
  u32 c = (n < NN) ? (cnt[n] + 1u) : 0u;   // +1 self loop
  u32 pre = c;                          // wave-inclusive prefix sum
  #pragma unroll
  for (int off=1; off<64; off<<=1){
    u32 v = __shfl_up(pre, off);
    if (lane >= off) pre += v;
  }
  u32 tot = __shfl(pre, 63);
  u32 base = 0;
  if (lane == 63) base = atomicAdd(counter, tot);
  base = __shfl(base, 63);
  if (n < NN){
    u32 s = base + pre - c;             // exclusive
    start[n] = s; pos[n] = s;
    dinv[n] = rsqrtf((float)c);
    cnt[n] = c;                         // store total (incl self loop)
  }
}
__global__ void k_fill(const int* __restrict__ src, const int* __restrict__ dst,
                       u32* __restrict__ pos, u16s* __restrict__ col,
                       const float* __restrict__ dinv, float* __restrict__ nrmE){
  int e = blockIdx.x*blockDim.x + threadIdx.x;
  if (e < ET){
    int s, d;
    if (e < EE){ s = src[e]; d = dst[e]; } else { s = d = e - EE; }
    u32 idx = atomicAdd(&pos[d], 1u);
    col[idx] = (u16s)s;
    nrmE[idx] = dinv[s] * dinv[d];
  }
}

// ---------------- x -> f16 (streaming) ----------------
__global__ void k_x16(const float* __restrict__ x, f16* __restrict__ o){
  int i = blockIdx.x*blockDim.x + threadIdx.x;
  if (i >= NN*HID/8) return;
  const float4 u0 = *(const float4*)(x + (size_t)i*8);
  const float4 u1 = *(const float4*)(x + (size_t)i*8 + 4);
  f16x8 v;
  v[0]=(f16)u0.x; v[1]=(f16)u0.y; v[2]=(f16)u0.z; v[3]=(f16)u0.w;
  v[4]=(f16)u1.x; v[5]=(f16)u1.y; v[6]=(f16)u1.z; v[7]=(f16)u1.w;
  *(f16x8*)(o + (size_t)i*8) = v;
}

// ---------------- all weight splits in one kernel ----------------
// W[K=256][NC] f32 row-major -> hi/lo f16 col-major
#define W1N (HID*HID)
__global__ void k_wsplit_all(const float* __restrict__ w1, const float* __restrict__ watt,
    const float* __restrict__ wmu, const float* __restrict__ wls,
    f16* __restrict__ w1h, f16* __restrict__ w1l,
    f16* __restrict__ wah, f16* __restrict__ wal,
    f16* __restrict__ wch, f16* __restrict__ wcl){
  int e = blockIdx.x*blockDim.x + threadIdx.x;
  const float* W; f16 *H, *L; int NC, coff = 0, idx;
  if (e < W1N){ W=w1; H=w1h; L=w1l; NC=HID; idx=e; }
  else if (e < 2*W1N){ W=watt; H=wah; L=wal; NC=HID; idx=e-W1N; }
  else if (e < 2*W1N + OC*HID){ W=wmu; H=wch; L=wcl; NC=OC; idx=e-2*W1N; }
  else if (e < 2*W1N + 2*OC*HID){ W=wls; H=wch; L=wcl; NC=OC; coff=OC; idx=e-2*W1N-OC*HID; }
  else return;
  int c = idx / HID, k = idx % HID;
  float w = W[(size_t)k*NC + c];
  f16 hi = (f16)w;
  f16 lo = (f16)(w - (float)hi);
  H[(size_t)(c+coff)*HID + k] = hi;
  L[(size_t)(c+coff)*HID + k] = lo;
}

// ---------------- LDS-staged GEMM (f16 A, 2-pass f16 W, MR=4 rows=64/block) ----------------
// Per K-step (32 k): block stages W hi/lo slab (all NC cols) into LDS (coalesced,
// independent loads), then waves read fragments via ds_read_b128. 80B/col padding
// spreads 16-lane col-groups over all eight 16B super-banks (conflict-free).
#define COLB 80
template<int NC, int NF>
__global__ __launch_bounds__(256) void k_gemm_lds(const f16* __restrict__ A,
    const f16* __restrict__ Whi, const f16* __restrict__ Wlo, f16* __restrict__ Cout){
  __shared__ char sm[2*NC*COLB];
  const int tid = threadIdx.x;
  const int w = tid >> 6, lane = tid & 63;
  const int r = lane & 15, g = lane >> 4;
  const int row0 = blockIdx.x * 64;
  const int wcol = w * (NF*16);
  f32x4 acc[4][NF];
  #pragma unroll
  for (int m=0;m<4;++m)
    #pragma unroll
    for (int j=0;j<NF;++j){ f32x4 z = {0.f,0.f,0.f,0.f}; acc[m][j] = z; }
  for (int kk=0; kk<8; ++kk){
    __syncthreads();
    // stage slab kk: NC*8 chunks of 16B (hi then lo), branch uniform per q
    #pragma unroll
    for (int q=0; q<NC/32; ++q){
      const int s = tid + 256*q;
      const f16* src; int dstb;
      if (s < NC*4){
        const int c = s >> 2, kc = s & 3;
        src = Whi + (size_t)c*HID + kk*32 + kc*8;
        dstb = c*COLB + kc*16;
      } else {
        const int s2 = s - NC*4;
        const int c = s2 >> 2, kc = s2 & 3;
        src = Wlo + (size_t)c*HID + kk*32 + kc*8;
        dstb = NC*COLB + c*COLB + kc*16;
      }
      *(f16x8*)(sm + dstb) = *(const f16x8*)src;
    }
    __syncthreads();
    const int k0 = kk*32 + g*8;
    f16x8 a[4];
    #pragma unroll
    for (int m=0;m<4;++m){
      const int row = row0 + m*16 + r;
      f16x8 z = {0,0,0,0,0,0,0,0};
      a[m] = (row < NN) ? *(const f16x8*)(A + (size_t)row*HID + k0) : z;
    }
    #pragma unroll
    for (int j=0;j<NF;++j){
      const int c = wcol + j*16 + r;
      const f16x8 wh = *(const f16x8*)(sm + c*COLB + g*16);
      const f16x8 wl = *(const f16x8*)(sm + NC*COLB + c*COLB + g*16);
      #pragma unroll
      for (int m=0;m<4;++m){
        acc[m][j] = __builtin_amdgcn_mfma_f32_16x16x32_f16(a[m], wh, acc[m][j], 0, 0, 0);
        acc[m][j] = __builtin_amdgcn_mfma_f32_16x16x32_f16(a[m], wl, acc[m][j], 0, 0, 0);
      }
    }
  }
  #pragma unroll
  for (int j=0;j<NF;++j){
    const int c = wcol + j*16 + r;
    #pragma unroll
    for (int m=0;m<4;++m){
      #pragma unroll
      for (int q=0;q<4;++q){
        const int row = row0 + m*16 + g*4 + q;
        if (row < NN) Cout[(size_t)row*NC + c] = (f16)acc[m][j][q];
      }
    }
  }
}

// ---------------- LDS-staged GAT GEMM + fused attention coefficients ----------------
// Wave w covers cols [64w,64w+64) == heads {2w, 2w+1}; per-head attention dots
// reduce within the wave (shuffle over r-lanes), no extra LDS.
__global__ __launch_bounds__(256) void k_gemm_att(const f16* __restrict__ A,
    const f16* __restrict__ Whi, const f16* __restrict__ Wlo,
    const float* __restrict__ atts, const float* __restrict__ attd,
    f16* __restrict__ Cout, float* __restrict__ a_src, float* __restrict__ a_dst){
  __shared__ char sm[2*HID*COLB];
  const int tid = threadIdx.x;
  const int w = tid >> 6, lane = tid & 63;
  const int r = lane & 15, g = lane >> 4;
  const int row0 = blockIdx.x * 64;
  const int wcol = w * 64;
  f32x4 acc[4][4];
  #pragma unroll
  for (int m=0;m<4;++m)
    #pragma unroll
    for (int j=0;j<4;++j){ f32x4 z = {0.f,0.f,0.f,0.f}; acc[m][j] = z; }
  for (int kk=0; kk<8; ++kk){
    __syncthreads();
    #pragma unroll
    for (int q=0; q<8; ++q){
      const int s = tid + 256*q;
      const f16* src; int dstb;
      if (s < HID*4){
        const int c = s >> 2, kc = s & 3;
        src = Whi + (size_t)c*HID + kk*32 + kc*8;
        dstb = c*COLB + kc*16;
      } else {
        const int s2 = s - HID*4;
        const int c = s2 >> 2, kc = s2 & 3;
        src = Wlo + (size_t)c*HID + kk*32 + kc*8;
        dstb = HID*COLB + c*COLB + kc*16;
      }
      *(f16x8*)(sm + dstb) = *(const f16x8*)src;
    }
    __syncthreads();
    const int k0 = kk*32 + g*8;
    f16x8 a[4];
    #pragma unroll
    for (int m=0;m<4;++m){
      const int row = row0 + m*16 + r;
      f16x8 z = {0,0,0,0,0,0,0,0};
      a[m] = (row < NN) ? *(const f16x8*)(A + (size_t)row*HID + k0) : z;
    }
    #pragma unroll
    for (int j=0;j<4;++j){
      const int c = wcol + j*16 + r;
      const f16x8 wh = *(const f16x8*)(sm + c*COLB + g*16);
      const f16x8 wl = *(const f16x8*)(sm + HID*COLB + c*COLB + g*16);
      #pragma unroll
      for (int m=0;m<4;++m){
        acc[m][j] = __builtin_amdgcn_mfma_f32_16x16x32_f16(a[m], wh, acc[m][j], 0, 0, 0);
        acc[m][j] = __builtin_amdgcn_mfma_f32_16x16x32_f16(a[m], wl, acc[m][j], 0, 0, 0);
      }
    }
  }
  float atv[4], adv[4];
  #pragma unroll
  for (int j=0;j<4;++j){ atv[j] = atts[wcol+j*16+r]; adv[j] = attd[wcol+j*16+r]; }
  #pragma unroll
  for (int m=0;m<4;++m){
    float ps[2][4] = {{0,0,0,0},{0,0,0,0}};   // [head_local][q]
    float pd[2][4] = {{0,0,0,0},{0,0,0,0}};
    #pragma unroll
    for (int j=0;j<4;++j){
      const int c = wcol + j*16 + r;
      const int hl = j >> 1;
      #pragma unroll
      for (int q=0;q<4;++q){
        const int row = row0 + m*16 + g*4 + q;
        const float v = acc[m][j][q];
        if (row < NN) Cout[(size_t)row*HID + c] = (f16)v;
        ps[hl][q] = fmaf(v, atv[j], ps[hl][q]);
        pd[hl][q] = fmaf(v, adv[j], pd[hl][q]);
      }
    }
    #pragma unroll
    for (int hl=0;hl<2;++hl)
      #pragma unroll
      for (int q=0;q<4;++q){
        float s = ps[hl][q], d = pd[hl][q];
        s += __shfl_xor(s,1); s += __shfl_xor(s,2); s += __shfl_xor(s,4); s += __shfl_xor(s,8);
        d += __shfl_xor(d,1); d += __shfl_xor(d,2); d += __shfl_xor(d,4); d += __shfl_xor(d,8);
        if (r == 0){
          const int row = row0 + m*16 + g*4 + q;
          if (row < NN){
            a_src[(size_t)row*NH + 2*w + hl] = s;
            a_dst[(size_t)row*NH + 2*w + hl] = d;
          }
        }
      }
  }
}

// ---------------- layer-1 agg: wave/node, 256-dim f16 gather, +bias+gelu ----------------
__global__ __launch_bounds__(256) void k_aggH(const f16* __restrict__ feat,
    const u16s* __restrict__ col, const u32* __restrict__ start, const u32* __restrict__ cnt,
    const float* __restrict__ nrmE, const float* __restrict__ bias, f16* __restrict__ out){
  const int n = (int)((blockIdx.x*blockDim.x + threadIdx.x) >> 6);
  if (n >= NN) return;
  const int lane = threadIdx.x & 63;
  const u32 b = start[n], e = b + cnt[n];
  const int fo = lane*4;
  float a0=0.f,a1=0.f,a2=0.f,a3=0.f;
  u32 s0 = col[b];
  float w0 = nrmE[b];
  f16x4 v0 = *(const f16x4*)(feat + (size_t)s0*HID + fo);
  for (u32 k=b+1; k<e; ++k){
    const u32 s1 = col[k];
    const float w1 = nrmE[k];
    const f16x4 v1 = *(const f16x4*)(feat + (size_t)s1*HID + fo);
    a0 = fmaf(w0, (float)v0.x, a0);
    a1 = fmaf(w0, (float)v0.y, a1);
    a2 = fmaf(w0, (float)v0.z, a2);
    a3 = fmaf(w0, (float)v0.w, a3);
    v0 = v1; w0 = w1;
  }
  a0 = fmaf(w0, (float)v0.x, a0);
  a1 = fmaf(w0, (float)v0.y, a1);
  a2 = fmaf(w0, (float)v0.z, a2);
  a3 = fmaf(w0, (float)v0.w, a3);
  const float4 bv = *(const float4*)(bias + fo);
  f16x4 o;
  o.x = (f16)geluf(a0 + bv.x);
  o.y = (f16)geluf(a1 + bv.y);
  o.z = (f16)geluf(a2 + bv.z);
  o.w = (f16)geluf(a3 + bv.w);
  *(f16x4*)(out + (size_t)n*HID + fo) = o;
}

// ---------------- fused GAT: single-pass softmax-free weighted gather + bias + relu ----------------
// out = (sum_k exp(e_k) v_k) / (sum_k exp(e_k)); e_k ~O(5) so unshifted exp is safe.
__global__ __launch_bounds__(256) void k_gat_fused(const f16* __restrict__ gfeat,
    const u16s* __restrict__ col, const u32* __restrict__ start, const u32* __restrict__ cnt,
    const float* __restrict__ a_src, const float* __restrict__ a_dst,
    const float* __restrict__ b_att, f16* __restrict__ h2){
  const int n = (int)((blockIdx.x*blockDim.x + threadIdx.x) >> 6);
  if (n >= NN) return;
  const int lane = threadIdx.x & 63;
  const int head = lane >> 3;            // feats [32h,32h+32) <-> lanes [8h,8h+8)
  const int fo = lane*4;
  const u32 b = start[n], e = b + cnt[n];
  const float ad = a_dst[(size_t)n*NH + head];
  float a0=0.f,a1=0.f,a2=0.f,a3=0.f,sp=0.f;
  u32 s0 = col[b];
  float as0 = a_src[(size_t)s0*NH + head];
  f16x4 v0 = *(const f16x4*)(gfeat + (size_t)s0*HID + fo);
  for (u32 k=b+1; k<e; ++k){
    const u32 s1 = col[k];
    const float as1 = a_src[(size_t)s1*NH + head];
    const f16x4 v1 = *(const f16x4*)(gfeat + (size_t)s1*HID + fo);
    const float p = expf(leakyf(as0 + ad));
    sp += p;
    a0 = fmaf(p, (float)v0.x, a0);
    a1 = fmaf(p, (float)v0.y, a1);
    a2 = fmaf(p, (float)v0.z, a2);
    a3 = fmaf(p, (float)v0.w, a3);
    v0 = v1; as0 = as1;
  }
  const float p = expf(leakyf(as0 + ad));
  sp += p;
  a0 = fmaf(p, (float)v0.x, a0);
  a1 = fmaf(p, (float)v0.y, a1);
  a2 = fmaf(p, (float)v0.z, a2);
  a3 = fmaf(p, (float)v0.w, a3);
  const float inv_s = 1.f / sp;
  const float4 bv = *(const float4*)(b_att + fo);
  f16x4 o;
  o.x = (f16)fmaxf(fmaf(a0, inv_s, bv.x), 0.f);
  o.y = (f16)fmaxf(fmaf(a1, inv_s, bv.y), 0.f);
  o.z = (f16)fmaxf(fmaf(a2, inv_s, bv.z), 0.f);
  o.w = (f16)fmaxf(fmaf(a3, inv_s, bv.w), 0.f);
  *(f16x4*)(h2 + (size_t)n*HID + fo) = o;
}

// ---------------- layer-3 agg: 128-dim, 4 edges/iter, 16B loads, f32 out (mu | logstd) ----------------
__global__ __launch_bounds__(256) void k_agg_out(const f16* __restrict__ p,
    const u16s* __restrict__ col, const u32* __restrict__ start, const u32* __restrict__ cnt,
    const float* __restrict__ nrmE, const float* __restrict__ b_mu, const float* __restrict__ b_ls,
    float* __restrict__ out){
  const int n = (int)((blockIdx.x*blockDim.x + threadIdx.x) >> 6);
  if (n >= NN) return;
  const int lane = threadIdx.x & 63;
  const int q4 = lane >> 4, l4 = lane & 15;
  const int fo = l4*8;                 // 8 f16 = 16 B per lane (128-dim row)
  const u32 b = start[n], c = cnt[n];
  float acc[8] = {0.f,0.f,0.f,0.f,0.f,0.f,0.f,0.f};
  u32 i0 = (u32)q4;
  bool v0 = i0 < c;
  u32 idx0 = b + (v0 ? i0 : 0u);
  u32 s0 = col[idx0];
  float nrm0 = v0 ? nrmE[idx0] : 0.f;
  f16x8 f0 = *(const f16x8*)(p + (size_t)s0*PC + fo);
  for (u32 k=4; k<c; k+=4){
    const u32 i1 = k + (u32)q4;
    const bool v1 = i1 < c;
    const u32 idx1 = b + (v1 ? i1 : 0u);
    const u32 s1 = col[idx1];
    const float nrm1 = v1 ? nrmE[idx1] : 0.f;
    const f16x8 f1 = *(const f16x8*)(p + (size_t)s1*PC + fo);
    #pragma unroll
    for (int j=0;j<8;++j) acc[j] = fmaf(nrm0, (float)f0[j], acc[j]);
    f0 = f1; nrm0 = nrm1;
  }
  #pragma unroll
  for (int j=0;j<8;++j) acc[j] = fmaf(nrm0, (float)f0[j], acc[j]);
  #pragma unroll
  for (int j=0;j<8;++j){
    acc[j] += __shfl_xor(acc[j], 16);
    acc[j] += __shfl_xor(acc[j], 32);
  }
  if (q4 == 0){
    if (l4 < 8){
      const int cc = fo;               // mu cols 0..63
      float4 o0 = make_float4(acc[0]+b_mu[cc], acc[1]+b_mu[cc+1], acc[2]+b_mu[cc+2], acc[3]+b_mu[cc+3]);
      float4 o1 = make_float4(acc[4]+b_mu[cc+4], acc[5]+b_mu[cc+5], acc[6]+b_mu[cc+6], acc[7]+b_mu[cc+7]);
      *(float4*)(out + (size_t)n*OC + cc) = o0;
      *(float4*)(out + (size_t)n*OC + cc + 4) = o1;
    } else {
      const int cc = fo - OC;          // logstd cols 0..63
      float* o = out + (size_t)NN*OC + (size_t)n*OC + cc;
      float4 o0 = make_float4(acc[0]+b_ls[cc], acc[1]+b_ls[cc+1], acc[2]+b_ls[cc+2], acc[3]+b_ls[cc+3]);
      float4 o1 = make_float4(acc[4]+b_ls[cc+4], acc[5]+b_ls[cc+5], acc[6]+b_ls[cc+6], acc[7]+b_ls[cc+7]);
      *(float4*)o = o0;
      *(float4*)(o + 4) = o1;
    }
  }
}

extern "C" void kernel_launch(void* const* d_in, const int* in_sizes, int n_in,
                              void* d_out, int out_size, void* d_ws, size_t ws_size,
                              hipStream_t stream){
  const float* x    = (const float*)d_in[0];
  const int*   ei   = (const int*)d_in[1];
  const float* w1   = (const float*)d_in[2];
  const float* b1   = (const float*)d_in[3];
  const float* watt = (const float*)d_in[4];
  const float* atts = (const float*)d_in[5];
  const float* attd = (const float*)d_in[6];
  const float* batt = (const float*)d_in[7];
  const float* wmu  = (const float*)d_in[8];
  const float* bmu  = (const float*)d_in[9];
  const float* wls  = (const float*)d_in[10];
  const float* bls  = (const float*)d_in[11];
  const int* esrc = ei;
  const int* edst = ei + EE;

  char* p = (char*)d_ws;
  f16* bufA = (f16*)p;  p += (size_t)NN*HID*2;   // 25.6 MB: g1 (x16@w1) -> h2
  f16* bufB = (f16*)p;  p += (size_t)NN*HID*2;   // 25.6 MB: h1 -> proj(128)
  f16* bufC = (f16*)p;  p += (size_t)NN*HID*2;   // 25.6 MB: x16 -> g (GAT feats)
  float* nrmE = (float*)p; p += (size_t)ET*4;    // 3.4 MB per-edge GCN norm
  f16* w1h   = (f16*)p;  p += (size_t)HID*HID*2;
  f16* w1l   = (f16*)p;  p += (size_t)HID*HID*2;
  f16* wahi  = (f16*)p;  p += (size_t)HID*HID*2;
  f16* walo  = (f16*)p;  p += (size_t)HID*HID*2;
  f16* wchi  = (f16*)p;  p += (size_t)PC*HID*2;
  f16* wclo  = (f16*)p;  p += (size_t)PC*HID*2;
  float* dinv = (float*)p; p += (size_t)NN*4;
  float* asr  = (float*)p; p += (size_t)NN*NH*4;
  float* ads  = (float*)p; p += (size_t)NN*NH*4;
  u32*   cnt  = (u32*)p;   p += (size_t)NN*4;
  u32*   start= (u32*)p;   p += (size_t)NN*4;
  u32*   pos  = (u32*)p;   p += (size_t)NN*4;
  u32*   counter = (u32*)p; p += 256;
  u16s*  colU = (u16s*)p;  p += (size_t)ET*2;    // 1.7 MB

  const int TB = 256;
  // CSR build (memset init; self-loop folded into k_alloc)
  hipMemsetAsync(cnt, 0, (size_t)NN*4, stream);
  hipMemsetAsync(counter, 0, 4, stream);
  k_count<<<(EE+TB-1)/TB, TB, 0, stream>>>(edst, cnt);
  k_alloc<<<(NN+TB-1)/TB, TB, 0, stream>>>(cnt, counter, start, pos, dinv);
  k_fill <<<(ET+TB-1)/TB, TB, 0, stream>>>(esrc, edst, pos, colU, dinv, nrmE);
  // weight splits (single launch) + x -> f16
  k_wsplit_all<<<(2*W1N + 2*OC*HID + TB-1)/TB, TB, 0, stream>>>(
      w1, watt, wmu, wls, w1h, w1l, wahi, walo, wchi, wclo);
  k_x16<<<(NN*HID/8 + TB-1)/TB, TB, 0, stream>>>(x, bufC);

  const int NWB = NN/4;             // wave-per-node kernels (4 waves/block)
  const int G64 = (NN + 63)/64;     // 64-row GEMM blocks
  // layer 1: g1 = x16@w1 ; h1 = gelu(agg(g1) + b1)
  k_gemm_lds<HID,4><<<G64, TB, 0, stream>>>(bufC, w1h, w1l, bufA);
  k_aggH<<<NWB, TB, 0, stream>>>(bufA, colU, start, cnt, nrmE, b1, bufB);
  // GAT: g = h1@w_att (+fused att coefs) ; single-pass softmax-free aggregate
  k_gemm_att<<<G64, TB, 0, stream>>>(bufB, wahi, walo, atts, attd, bufC, asr, ads);
  k_gat_fused<<<NWB, TB, 0, stream>>>(bufC, colU, start, cnt, asr, ads, batt, bufA);
  // layer 3: project first (128 cols = mu||ls), then one 128-dim gather -> d_out
  k_gemm_lds<PC,2><<<G64, TB, 0, stream>>>(bufA, wchi, wclo, bufB);
  k_agg_out<<<NWB, TB, 0, stream>>>(bufB, colU, start, cnt, nrmE, bmu, bls, (float*)d_out);
}

// Round 18
// 397.926 us; speedup vs baseline: 1.1845x; 1.0144x over previous
//
#include <hip/hip_runtime.h>

#define NN 50000
#define EE 800000
#define ET (EE + NN)
#define HID 256
#define NH 8
#define HC 32
#define OC 64
#define PC 128   // layer-3 projected width (mu||logstd)

typedef unsigned int u32;
typedef unsigned short u16s;
typedef _Float16 f16;
typedef __attribute__((ext_vector_type(8))) _Float16 f16x8;
typedef __attribute__((ext_vector_type(4))) _Float16 f16x4;
typedef __attribute__((ext_vector_type(4))) float f32x4;

static __device__ __forceinline__ float geluf(float x){
  float t = tanhf(0.7978845608028654f*(x + 0.044715f*x*x*x));
  return 0.5f*x*(1.0f+t);
}
static __device__ __forceinline__ float leakyf(float x){
  return x > 0.0f ? x : 0.2f*x;
}

// ---------------- fused prep: edge-count atomics | x->f16 | weight splits ----------------
// Independent work items packed into one launch (block-range partition).
#define W1N (HID*HID)
#define NB_CNT ((EE + 255)/256)                 // 3125
#define NB_X16 ((NN*HID/8 + 255)/256)           // 6250
#define NB_WSP ((2*W1N + 2*OC*HID + 255)/256)   // 640
__global__ void k_prep(const int* __restrict__ dst, u32* __restrict__ cnt,
    const float* __restrict__ x, f16* __restrict__ x16,
    const float* __restrict__ w1, const float* __restrict__ watt,
    const float* __restrict__ wmu, const float* __restrict__ wls,
    f16* __restrict__ w1h, f16* __restrict__ w1l,
    f16* __restrict__ wah, f16* __restrict__ wal,
    f16* __restrict__ wch, f16* __restrict__ wcl){
  const int bid = blockIdx.x;
  if (bid < NB_CNT){
    int e = bid*256 + threadIdx.x;
    if (e < EE) atomicAdd(&cnt[dst[e]], 1u);
  } else if (bid < NB_CNT + NB_X16){
    int i = (bid - NB_CNT)*256 + threadIdx.x;
    if (i >= NN*HID/8) return;
    const float4 u0 = *(const float4*)(x + (size_t)i*8);
    const float4 u1 = *(const float4*)(x + (size_t)i*8 + 4);
    f16x8 v;
    v[0]=(f16)u0.x; v[1]=(f16)u0.y; v[2]=(f16)u0.z; v[3]=(f16)u0.w;
    v[4]=(f16)u1.x; v[5]=(f16)u1.y; v[6]=(f16)u1.z; v[7]=(f16)u1.w;
    *(f16x8*)(x16 + (size_t)i*8) = v;
  } else {
    int e = (bid - NB_CNT - NB_X16)*256 + threadIdx.x;
    const float* W; f16 *H, *L; int NC, coff = 0, idx;
    if (e < W1N){ W=w1; H=w1h; L=w1l; NC=HID; idx=e; }
    else if (e < 2*W1N){ W=watt; H=wah; L=wal; NC=HID; idx=e-W1N; }
    else if (e < 2*W1N + OC*HID){ W=wmu; H=wch; L=wcl; NC=OC; idx=e-2*W1N; }
    else if (e < 2*W1N + 2*OC*HID){ W=wls; H=wch; L=wcl; NC=OC; coff=OC; idx=e-2*W1N-OC*HID; }
    else return;
    int c = idx / HID, k = idx % HID;
    float w = W[(size_t)k*NC + c];
    f16 hi = (f16)w;
    f16 lo = (f16)(w - (float)hi);
    H[(size_t)(c+coff)*HID + k] = hi;
    L[(size_t)(c+coff)*HID + k] = lo;
  }
}

// wave-aggregated bump allocation: 1 atomic per wave (G12). Adds self-loop (+1).
__global__ void k_alloc(u32* __restrict__ cnt, u32* counter,
                        u32* __restrict__ start, u32* __restrict__ pos,
                        float* __restrict__ dinv){
  int n = blockIdx.x*blockDim.x + threadIdx.x;
  const int lane = threadIdx.x & 63;
  u32 c = (n < NN) ? (cnt[n] + 1u) : 0u;   // +1 self loop
  u32 pre = c;                          // wave-inclusive prefix sum
  #pragma unroll
  for (int off=1; off<64; off<<=1){
    u32 v = __shfl_up(pre, off);
    if (lane >= off) pre += v;
  }
  u32 tot = __shfl(pre, 63);
  u32 base = 0;
  if (lane == 63) base = atomicAdd(counter, tot);
  base = __shfl(base, 63);
  if (n < NN){
    u32 s = base + pre - c;             // exclusive
    start[n] = s; pos[n] = s;
    dinv[n] = rsqrtf((float)c);
    cnt[n] = c;                         // store total (incl self loop)
  }
}
__global__ void k_fill(const int* __restrict__ src, const int* __restrict__ dst,
                       u32* __restrict__ pos, u16s* __restrict__ col,
                       const float* __restrict__ dinv, float* __restrict__ nrmE){
  int e = blockIdx.x*blockDim.x + threadIdx.x;
  if (e < ET){
    int s, d;
    if (e < EE){ s = src[e]; d = dst[e]; } else { s = d = e - EE; }
    u32 idx = atomicAdd(&pos[d], 1u);
    col[idx] = (u16s)s;
    nrmE[idx] = dinv[s] * dinv[d];
  }
}

// ---------------- LDS-staged GEMM (f16 A, 2-pass f16 W, rows=64/block) ----------------
// Per K-step (32 k): block stages W hi/lo slab (all NC cols) into LDS (coalesced,
// independent loads), then waves read fragments via ds_read_b128. 80B/col padding
// spreads 16-lane col-groups over all eight 16B super-banks (conflict-free).
#define COLB 80
template<int NC, int NF>
__global__ __launch_bounds__(256) void k_gemm_lds(const f16* __restrict__ A,
    const f16* __restrict__ Whi, const f16* __restrict__ Wlo, f16* __restrict__ Cout){
  __shared__ char sm[2*NC*COLB];
  const int tid = threadIdx.x;
  const int w = tid >> 6, lane = tid & 63;
  const int r = lane & 15, g = lane >> 4;
  const int row0 = blockIdx.x * 64;
  const int wcol = w * (NF*16);
  f32x4 acc[4][NF];
  #pragma unroll
  for (int m=0;m<4;++m)
    #pragma unroll
    for (int j=0;j<NF;++j){ f32x4 z = {0.f,0.f,0.f,0.f}; acc[m][j] = z; }
  for (int kk=0; kk<8; ++kk){
    __syncthreads();
    #pragma unroll
    for (int q=0; q<NC/32; ++q){
      const int s = tid + 256*q;
      const f16* src; int dstb;
      if (s < NC*4){
        const int c = s >> 2, kc = s & 3;
        src = Whi + (size_t)c*HID + kk*32 + kc*8;
        dstb = c*COLB + kc*16;
      } else {
        const int s2 = s - NC*4;
        const int c = s2 >> 2, kc = s2 & 3;
        src = Wlo + (size_t)c*HID + kk*32 + kc*8;
        dstb = NC*COLB + c*COLB + kc*16;
      }
      *(f16x8*)(sm + dstb) = *(const f16x8*)src;
    }
    __syncthreads();
    const int k0 = kk*32 + g*8;
    f16x8 a[4];
    #pragma unroll
    for (int m=0;m<4;++m){
      const int row = row0 + m*16 + r;
      f16x8 z = {0,0,0,0,0,0,0,0};
      a[m] = (row < NN) ? *(const f16x8*)(A + (size_t)row*HID + k0) : z;
    }
    #pragma unroll
    for (int j=0;j<NF;++j){
      const int c = wcol + j*16 + r;
      const f16x8 wh = *(const f16x8*)(sm + c*COLB + g*16);
      const f16x8 wl = *(const f16x8*)(sm + NC*COLB + c*COLB + g*16);
      #pragma unroll
      for (int m=0;m<4;++m){
        acc[m][j] = __builtin_amdgcn_mfma_f32_16x16x32_f16(a[m], wh, acc[m][j], 0, 0, 0);
        acc[m][j] = __builtin_amdgcn_mfma_f32_16x16x32_f16(a[m], wl, acc[m][j], 0, 0, 0);
      }
    }
  }
  #pragma unroll
  for (int j=0;j<NF;++j){
    const int c = wcol + j*16 + r;
    #pragma unroll
    for (int m=0;m<4;++m){
      #pragma unroll
      for (int q=0;q<4;++q){
        const int row = row0 + m*16 + g*4 + q;
        if (row < NN) Cout[(size_t)row*NC + c] = (f16)acc[m][j][q];
      }
    }
  }
}

// ---------------- LDS-staged GAT GEMM + fused attention coefficients ----------------
__global__ __launch_bounds__(256) void k_gemm_att(const f16* __restrict__ A,
    const f16* __restrict__ Whi, const f16* __restrict__ Wlo,
    const float* __restrict__ atts, const float* __restrict__ attd,
    f16* __restrict__ Cout, float* __restrict__ a_src, float* __restrict__ a_dst){
  __shared__ char sm[2*HID*COLB];
  const int tid = threadIdx.x;
  const int w = tid >> 6, lane = tid & 63;
  const int r = lane & 15, g = lane >> 4;
  const int row0 = blockIdx.x * 64;
  const int wcol = w * 64;
  f32x4 acc[4][4];
  #pragma unroll
  for (int m=0;m<4;++m)
    #pragma unroll
    for (int j=0;j<4;++j){ f32x4 z = {0.f,0.f,0.f,0.f}; acc[m][j] = z; }
  for (int kk=0; kk<8; ++kk){
    __syncthreads();
    #pragma unroll
    for (int q=0; q<8; ++q){
      const int s = tid + 256*q;
      const f16* src; int dstb;
      if (s < HID*4){
        const int c = s >> 2, kc = s & 3;
        src = Whi + (size_t)c*HID + kk*32 + kc*8;
        dstb = c*COLB + kc*16;
      } else {
        const int s2 = s - HID*4;
        const int c = s2 >> 2, kc = s2 & 3;
        src = Wlo + (size_t)c*HID + kk*32 + kc*8;
        dstb = HID*COLB + c*COLB + kc*16;
      }
      *(f16x8*)(sm + dstb) = *(const f16x8*)src;
    }
    __syncthreads();
    const int k0 = kk*32 + g*8;
    f16x8 a[4];
    #pragma unroll
    for (int m=0;m<4;++m){
      const int row = row0 + m*16 + r;
      f16x8 z = {0,0,0,0,0,0,0,0};
      a[m] = (row < NN) ? *(const f16x8*)(A + (size_t)row*HID + k0) : z;
    }
    #pragma unroll
    for (int j=0;j<4;++j){
      const int c = wcol + j*16 + r;
      const f16x8 wh = *(const f16x8*)(sm + c*COLB + g*16);
      const f16x8 wl = *(const f16x8*)(sm + HID*COLB + c*COLB + g*16);
      #pragma unroll
      for (int m=0;m<4;++m){
        acc[m][j] = __builtin_amdgcn_mfma_f32_16x16x32_f16(a[m], wh, acc[m][j], 0, 0, 0);
        acc[m][j] = __builtin_amdgcn_mfma_f32_16x16x32_f16(a[m], wl, acc[m][j], 0, 0, 0);
      }
    }
  }
  float atv[4], adv[4];
  #pragma unroll
  for (int j=0;j<4;++j){ atv[j] = atts[wcol+j*16+r]; adv[j] = attd[wcol+j*16+r]; }
  #pragma unroll
  for (int m=0;m<4;++m){
    float ps[2][4] = {{0,0,0,0},{0,0,0,0}};   // [head_local][q]
    float pd[2][4] = {{0,0,0,0},{0,0,0,0}};
    #pragma unroll
    for (int j=0;j<4;++j){
      const int c = wcol + j*16 + r;
      const int hl = j >> 1;
      #pragma unroll
      for (int q=0;q<4;++q){
        const int row = row0 + m*16 + g*4 + q;
        const float v = acc[m][j][q];
        if (row < NN) Cout[(size_t)row*HID + c] = (f16)v;
        ps[hl][q] = fmaf(v, atv[j], ps[hl][q]);
        pd[hl][q] = fmaf(v, adv[j], pd[hl][q]);
      }
    }
    #pragma unroll
    for (int hl=0;hl<2;++hl)
      #pragma unroll
      for (int q=0;q<4;++q){
        float s = ps[hl][q], d = pd[hl][q];
        s += __shfl_xor(s,1); s += __shfl_xor(s,2); s += __shfl_xor(s,4); s += __shfl_xor(s,8);
        d += __shfl_xor(d,1); d += __shfl_xor(d,2); d += __shfl_xor(d,4); d += __shfl_xor(d,8);
        if (r == 0){
          const int row = row0 + m*16 + g*4 + q;
          if (row < NN){
            a_src[(size_t)row*NH + 2*w + hl] = s;
            a_dst[(size_t)row*NH + 2*w + hl] = d;
          }
        }
      }
  }
}

// ---------------- layer-1 agg: wave/node, 256-dim f16 gather, +bias+gelu ----------------
__global__ __launch_bounds__(256) void k_aggH(const f16* __restrict__ feat,
    const u16s* __restrict__ col, const u32* __restrict__ start, const u32* __restrict__ cnt,
    const float* __restrict__ nrmE, const float* __restrict__ bias, f16* __restrict__ out){
  const int n = (int)((blockIdx.x*blockDim.x + threadIdx.x) >> 6);
  if (n >= NN) return;
  const int lane = threadIdx.x & 63;
  const u32 b = start[n], e = b + cnt[n];
  const int fo = lane*4;
  float a0=0.f,a1=0.f,a2=0.f,a3=0.f;
  u32 s0 = col[b];
  float w0 = nrmE[b];
  f16x4 v0 = *(const f16x4*)(feat + (size_t)s0*HID + fo);
  for (u32 k=b+1; k<e; ++k){
    const u32 s1 = col[k];
    const float w1 = nrmE[k];
    const f16x4 v1 = *(const f16x4*)(feat + (size_t)s1*HID + fo);
    a0 = fmaf(w0, (float)v0.x, a0);
    a1 = fmaf(w0, (float)v0.y, a1);
    a2 = fmaf(w0, (float)v0.z, a2);
    a3 = fmaf(w0, (float)v0.w, a3);
    v0 = v1; w0 = w1;
  }
  a0 = fmaf(w0, (float)v0.x, a0);
  a1 = fmaf(w0, (float)v0.y, a1);
  a2 = fmaf(w0, (float)v0.z, a2);
  a3 = fmaf(w0, (float)v0.w, a3);
  const float4 bv = *(const float4*)(bias + fo);
  f16x4 o;
  o.x = (f16)geluf(a0 + bv.x);
  o.y = (f16)geluf(a1 + bv.y);
  o.z = (f16)geluf(a2 + bv.z);
  o.w = (f16)geluf(a3 + bv.w);
  *(f16x4*)(out + (size_t)n*HID + fo) = o;
}

// ---------------- fused GAT: single-pass softmax-free weighted gather + bias + relu ----------------
// out = (sum_k exp(e_k) v_k) / (sum_k exp(e_k)); e_k ~O(5) so unshifted exp is safe.
__global__ __launch_bounds__(256) void k_gat_fused(const f16* __restrict__ gfeat,
    const u16s* __restrict__ col, const u32* __restrict__ start, const u32* __restrict__ cnt,
    const float* __restrict__ a_src, const float* __restrict__ a_dst,
    const float* __restrict__ b_att, f16* __restrict__ h2){
  const int n = (int)((blockIdx.x*blockDim.x + threadIdx.x) >> 6);
  if (n >= NN) return;
  const int lane = threadIdx.x & 63;
  const int head = lane >> 3;            // feats [32h,32h+32) <-> lanes [8h,8h+8)
  const int fo = lane*4;
  const u32 b = start[n], e = b + cnt[n];
  const float ad = a_dst[(size_t)n*NH + head];
  float a0=0.f,a1=0.f,a2=0.f,a3=0.f,sp=0.f;
  u32 s0 = col[b];
  float as0 = a_src[(size_t)s0*NH + head];
  f16x4 v0 = *(const f16x4*)(gfeat + (size_t)s0*HID + fo);
  for (u32 k=b+1; k<e; ++k){
    const u32 s1 = col[k];
    const float as1 = a_src[(size_t)s1*NH + head];
    const f16x4 v1 = *(const f16x4*)(gfeat + (size_t)s1*HID + fo);
    const float p = expf(leakyf(as0 + ad));
    sp += p;
    a0 = fmaf(p, (float)v0.x, a0);
    a1 = fmaf(p, (float)v0.y, a1);
    a2 = fmaf(p, (float)v0.z, a2);
    a3 = fmaf(p, (float)v0.w, a3);
    v0 = v1; as0 = as1;
  }
  const float p = expf(leakyf(as0 + ad));
  sp += p;
  a0 = fmaf(p, (float)v0.x, a0);
  a1 = fmaf(p, (float)v0.y, a1);
  a2 = fmaf(p, (float)v0.z, a2);
  a3 = fmaf(p, (float)v0.w, a3);
  const float inv_s = 1.f / sp;
  const float4 bv = *(const float4*)(b_att + fo);
  f16x4 o;
  o.x = (f16)fmaxf(fmaf(a0, inv_s, bv.x), 0.f);
  o.y = (f16)fmaxf(fmaf(a1, inv_s, bv.y), 0.f);
  o.z = (f16)fmaxf(fmaf(a2, inv_s, bv.z), 0.f);
  o.w = (f16)fmaxf(fmaf(a3, inv_s, bv.w), 0.f);
  *(f16x4*)(h2 + (size_t)n*HID + fo) = o;
}

// ---------------- layer-3 agg: 128-dim, 4 edges/iter, 16B loads, f32 out (mu | logstd) ----------------
__global__ __launch_bounds__(256) void k_agg_out(const f16* __restrict__ p,
    const u16s* __restrict__ col, const u32* __restrict__ start, const u32* __restrict__ cnt,
    const float* __restrict__ nrmE, const float* __restrict__ b_mu, const float* __restrict__ b_ls,
    float* __restrict__ out){
  const int n = (int)((blockIdx.x*blockDim.x + threadIdx.x) >> 6);
  if (n >= NN) return;
  const int lane = threadIdx.x & 63;
  const int q4 = lane >> 4, l4 = lane & 15;
  const int fo = l4*8;                 // 8 f16 = 16 B per lane (128-dim row)
  const u32 b = start[n], c = cnt[n];
  float acc[8] = {0.f,0.f,0.f,0.f,0.f,0.f,0.f,0.f};
  u32 i0 = (u32)q4;
  bool v0 = i0 < c;
  u32 idx0 = b + (v0 ? i0 : 0u);
  u32 s0 = col[idx0];
  float nrm0 = v0 ? nrmE[idx0] : 0.f;
  f16x8 f0 = *(const f16x8*)(p + (size_t)s0*PC + fo);
  for (u32 k=4; k<c; k+=4){
    const u32 i1 = k + (u32)q4;
    const bool v1 = i1 < c;
    const u32 idx1 = b + (v1 ? i1 : 0u);
    const u32 s1 = col[idx1];
    const float nrm1 = v1 ? nrmE[idx1] : 0.f;
    const f16x8 f1 = *(const f16x8*)(p + (size_t)s1*PC + fo);
    #pragma unroll
    for (int j=0;j<8;++j) acc[j] = fmaf(nrm0, (float)f0[j], acc[j]);
    f0 = f1; nrm0 = nrm1;
  }
  #pragma unroll
  for (int j=0;j<8;++j) acc[j] = fmaf(nrm0, (float)f0[j], acc[j]);
  #pragma unroll
  for (int j=0;j<8;++j){
    acc[j] += __shfl_xor(acc[j], 16);
    acc[j] += __shfl_xor(acc[j], 32);
  }
  if (q4 == 0){
    if (l4 < 8){
      const int cc = fo;               // mu cols 0..63
      float4 o0 = make_float4(acc[0]+b_mu[cc], acc[1]+b_mu[cc+1], acc[2]+b_mu[cc+2], acc[3]+b_mu[cc+3]);
      float4 o1 = make_float4(acc[4]+b_mu[cc+4], acc[5]+b_mu[cc+5], acc[6]+b_mu[cc+6], acc[7]+b_mu[cc+7]);
      *(float4*)(out + (size_t)n*OC + cc) = o0;
      *(float4*)(out + (size_t)n*OC + cc + 4) = o1;
    } else {
      const int cc = fo - OC;          // logstd cols 0..63
      float* o = out + (size_t)NN*OC + (size_t)n*OC + cc;
      float4 o0 = make_float4(acc[0]+b_ls[cc], acc[1]+b_ls[cc+1], acc[2]+b_ls[cc+2], acc[3]+b_ls[cc+3]);
      float4 o1 = make_float4(acc[4]+b_ls[cc+4], acc[5]+b_ls[cc+5], acc[6]+b_ls[cc+6], acc[7]+b_ls[cc+7]);
      *(float4*)o = o0;
      *(float4*)(o + 4) = o1;
    }
  }
}

extern "C" void kernel_launch(void* const* d_in, const int* in_sizes, int n_in,
                              void* d_out, int out_size, void* d_ws, size_t ws_size,
                              hipStream_t stream){
  const float* x    = (const float*)d_in[0];
  const int*   ei   = (const int*)d_in[1];
  const float* w1   = (const float*)d_in[2];
  const float* b1   = (const float*)d_in[3];
  const float* watt = (const float*)d_in[4];
  const float* atts = (const float*)d_in[5];
  const float* attd = (const float*)d_in[6];
  const float* batt = (const float*)d_in[7];
  const float* wmu  = (const float*)d_in[8];
  const float* bmu  = (const float*)d_in[9];
  const float* wls  = (const float*)d_in[10];
  const float* bls  = (const float*)d_in[11];
  const int* esrc = ei;
  const int* edst = ei + EE;

  char* p = (char*)d_ws;
  f16* bufA = (f16*)p;  p += (size_t)NN*HID*2;   // 25.6 MB: g1 (x16@w1) -> h2
  f16* bufB = (f16*)p;  p += (size_t)NN*HID*2;   // 25.6 MB: h1 -> proj(128)
  f16* bufC = (f16*)p;  p += (size_t)NN*HID*2;   // 25.6 MB: x16 -> g (GAT feats)
  float* nrmE = (float*)p; p += (size_t)ET*4;    // 3.4 MB per-edge GCN norm
  f16* w1h   = (f16*)p;  p += (size_t)HID*HID*2;
  f16* w1l   = (f16*)p;  p += (size_t)HID*HID*2;
  f16* wahi  = (f16*)p;  p += (size_t)HID*HID*2;
  f16* walo  = (f16*)p;  p += (size_t)HID*HID*2;
  f16* wchi  = (f16*)p;  p += (size_t)PC*HID*2;
  f16* wclo  = (f16*)p;  p += (size_t)PC*HID*2;
  float* dinv = (float*)p; p += (size_t)NN*4;
  float* asr  = (float*)p; p += (size_t)NN*NH*4;
  float* ads  = (float*)p; p += (size_t)NN*NH*4;
  u32*   cnt  = (u32*)p;   p += (size_t)NN*4;
  u32*   start= (u32*)p;   p += (size_t)NN*4;
  u32*   pos  = (u32*)p;   p += (size_t)NN*4;
  u32*   counter = (u32*)p; p += 256;
  u16s*  colU = (u16s*)p;  p += (size_t)ET*2;    // 1.7 MB

  const int TB = 256;
  // CSR init + fused prep (edge-count | x->f16 | weight splits)
  hipMemsetAsync(cnt, 0, (size_t)NN*4, stream);
  hipMemsetAsync(counter, 0, 4, stream);
  k_prep<<<NB_CNT + NB_X16 + NB_WSP, TB, 0, stream>>>(
      edst, cnt, x, bufC, w1, watt, wmu, wls,
      w1h, w1l, wahi, walo, wchi, wclo);
  k_alloc<<<(NN+TB-1)/TB, TB, 0, stream>>>(cnt, counter, start, pos, dinv);
  k_fill <<<(ET+TB-1)/TB, TB, 0, stream>>>(esrc, edst, pos, colU, dinv, nrmE);

  const int NWB = NN/4;             // wave-per-node kernels (4 waves/block)
  const int G64 = (NN + 63)/64;     // 64-row GEMM blocks
  // layer 1: g1 = x16@w1 ; h1 = gelu(agg(g1) + b1)
  k_gemm_lds<HID,4><<<G64, TB, 0, stream>>>(bufC, w1h, w1l, bufA);
  k_aggH<<<NWB, TB, 0, stream>>>(bufA, colU, start, cnt, nrmE, b1, bufB);
  // GAT: g = h1@w_att (+fused att coefs) ; single-pass softmax-free aggregate
  k_gemm_att<<<G64, TB, 0, stream>>>(bufB, wahi, walo, atts, attd, bufC, asr, ads);
  k_gat_fused<<<NWB, TB, 0, stream>>>(bufC, colU, start, cnt, asr, ads, batt, bufA);
  // layer 3: project first (128 cols = mu||ls), then one 128-dim gather -> d_out
  k_gemm_lds<PC,2><<<G64, TB, 0, stream>>>(bufA, wchi, wclo, bufB);
  k_agg_out<<<NWB, TB, 0, stream>>>(bufB, colU, start, cnt, nrmE, bmu, bls, (float*)d_out);
}